// Round 7
// baseline (2739.820 us; speedup 1.0000x reference)
//
#include <hip/hip_runtime.h>
#include <hip/hip_bf16.h>

// Sizes (fixed by the problem)
// B=4, D_MODEL=256, L=64*64=4096, D_INNER=512, D_STATE=16, DT_RANK=16, D_CONV=4
#define BSZ 4
#define DM 256
#define LSEQ 4096
#define ED 512
#define NST 16
#define LOG2E 1.44269504088896f

__device__ __forceinline__ float silu_f(float v) { return v / (1.f + expf(-v)); }
__device__ __forceinline__ float softplus_f(float v) { return v > 20.f ? v : log1pf(expf(v)); }

// ---------------------------------------------------------------------------
// Batched transpose: out[b][c][r] = in[b][r][c]   (in: (B,R,C))
// ---------------------------------------------------------------------------
__global__ __launch_bounds__(256) void transpose_brc(const float* __restrict__ in,
                                                     float* __restrict__ out,
                                                     int R, int C) {
  __shared__ float tile[32][33];
  int b = blockIdx.z;
  int r0 = blockIdx.y * 32, c0 = blockIdx.x * 32;
  int tx = threadIdx.x, ty = threadIdx.y;  // block (32,8)
  #pragma unroll
  for (int i = ty; i < 32; i += 8)
    tile[i][tx] = in[((size_t)b * R + r0 + i) * C + c0 + tx];
  __syncthreads();
  #pragma unroll
  for (int i = ty; i < 32; i += 8)
    out[((size_t)b * C + c0 + i) * R + r0 + tx] = tile[tx][i];
}

// ---------------------------------------------------------------------------
// RMSNorm over last dim (256). One wave per row, 4 rows per block.
// ---------------------------------------------------------------------------
__global__ __launch_bounds__(256) void rmsnorm_kernel(const float* __restrict__ in,
                                                      const float* __restrict__ w,
                                                      float* __restrict__ out) {
  int row = blockIdx.x * 4 + (threadIdx.x >> 6);
  int lane = threadIdx.x & 63;
  float4 v = *(const float4*)&in[(size_t)row * DM + lane * 4];
  float ss = v.x * v.x + v.y * v.y + v.z * v.z + v.w * v.w;
  #pragma unroll
  for (int off = 32; off; off >>= 1) ss += __shfl_xor(ss, off);
  float r = rsqrtf(ss * (1.f / DM) + 1e-5f);
  float4 wv = *(const float4*)&w[lane * 4];
  float4 o;
  o.x = v.x * r * wv.x; o.y = v.y * r * wv.y;
  o.z = v.z * r * wv.z; o.w = v.w * r * wv.w;
  *(float4*)&out[(size_t)row * DM + lane * 4] = o;
}

// ---------------------------------------------------------------------------
// Depthwise causal conv1d (K=4) + bias + SiLU.
// Input: x_in half of XZ (row stride 1024). Output: XC (B*L, 512).
// ---------------------------------------------------------------------------
__global__ __launch_bounds__(256) void conv_silu_kernel(const float* __restrict__ xz,
                                                        const float* __restrict__ cw,
                                                        const float* __restrict__ cb,
                                                        float* __restrict__ xc) {
  int idx = blockIdx.x * 256 + threadIdx.x;  // B*L*128
  int e4 = (idx & 127) * 4;
  int bt = idx >> 7;
  int t = bt & (LSEQ - 1);
  float wts[4][4];
  #pragma unroll
  for (int j = 0; j < 4; ++j) {
    float4 t4 = *(const float4*)&cw[(e4 + j) * 4];
    wts[j][0] = t4.x; wts[j][1] = t4.y; wts[j][2] = t4.z; wts[j][3] = t4.w;
  }
  float4 bv = *(const float4*)&cb[e4];
  float acc[4] = {bv.x, bv.y, bv.z, bv.w};
  #pragma unroll
  for (int k = 0; k < 4; ++k) {
    int tt = t - 3 + k;
    if (tt >= 0) {
      float4 xv = *(const float4*)&xz[((size_t)(bt + k - 3)) * 1024 + e4];
      acc[0] = fmaf(xv.x, wts[0][k], acc[0]);
      acc[1] = fmaf(xv.y, wts[1][k], acc[1]);
      acc[2] = fmaf(xv.z, wts[2][k], acc[2]);
      acc[3] = fmaf(xv.w, wts[3][k], acc[3]);
    }
  }
  float4 o;
  o.x = silu_f(acc[0]); o.y = silu_f(acc[1]);
  o.z = silu_f(acc[2]); o.w = silu_f(acc[3]);
  *(float4*)&xc[(size_t)bt * ED + e4] = o;
}

// ---------------------------------------------------------------------------
// Tiled fp32 GEMM, NT layout: C[m][n] = sum_k A[m][k] * Bw[n][k]
// AMODE 0: plain A (lda).  AMODE 1: gated A from XZ: y[m,k]*silu(z[m,k])
// EMODE 0: store.  EMODE 2: C += v (residual)
// ---------------------------------------------------------------------------
template <int BM, int BN, int BK, int TM, int TN, int AMODE, int EMODE>
__global__ __launch_bounds__(256) void gemm_nt(const float* __restrict__ A,
                                               const float* __restrict__ Bw,
                                               float* __restrict__ C,
                                               int M, int N, int K,
                                               int lda, int ldb, int ldc) {
  constexpr int TX = BN / TN, TY = BM / TM;
  static_assert(TX * TY == 256, "block must be 256 threads");
  __shared__ float As[BM][BK + 1];
  __shared__ float Bs[BN][BK + 1];
  const int tid = threadIdx.x;
  const int tx = tid % TX, ty = tid / TX;
  const int m0 = blockIdx.y * BM, n0 = blockIdx.x * BN;
  float acc[TM][TN] = {};
  constexpr int VPR = BK / 4;        // float4 per LDS row
  constexpr int RPP = 256 / VPR;     // rows per load pass
  const int lr = tid / VPR, lc = (tid % VPR) * 4;

  for (int k0 = 0; k0 < K; k0 += BK) {
    for (int r = lr; r < BM; r += RPP) {
      const size_t row = (size_t)(m0 + r);
      float4 v;
      if (AMODE == 0) {
        v = *(const float4*)&A[row * lda + k0 + lc];
      } else {
        float4 yv = *(const float4*)&A[row * 1024 + k0 + lc];
        float4 zv = *(const float4*)&A[row * 1024 + 512 + k0 + lc];
        v.x = yv.x * silu_f(zv.x); v.y = yv.y * silu_f(zv.y);
        v.z = yv.z * silu_f(zv.z); v.w = yv.w * silu_f(zv.w);
      }
      As[r][lc] = v.x; As[r][lc + 1] = v.y; As[r][lc + 2] = v.z; As[r][lc + 3] = v.w;
    }
    for (int r = lr; r < BN; r += RPP) {
      float4 v = *(const float4*)&Bw[(size_t)(n0 + r) * ldb + k0 + lc];
      Bs[r][lc] = v.x; Bs[r][lc + 1] = v.y; Bs[r][lc + 2] = v.z; Bs[r][lc + 3] = v.w;
    }
    __syncthreads();
    #pragma unroll
    for (int kk = 0; kk < BK; ++kk) {
      float a[TM], bb[TN];
      #pragma unroll
      for (int i = 0; i < TM; ++i) a[i] = As[ty * TM + i][kk];
      #pragma unroll
      for (int j = 0; j < TN; ++j) bb[j] = Bs[tx * TN + j][kk];
      #pragma unroll
      for (int i = 0; i < TM; ++i)
        #pragma unroll
        for (int j = 0; j < TN; ++j)
          acc[i][j] = fmaf(a[i], bb[j], acc[i][j]);
    }
    __syncthreads();
  }

  #pragma unroll
  for (int i = 0; i < TM; ++i) {
    const size_t gm = (size_t)m0 + ty * TM + i;
    #pragma unroll
    for (int j = 0; j < TN; ++j) {
      const int gn = n0 + tx * TN + j;
      float v = acc[i][j];
      if (EMODE == 2) C[gm * ldc + gn] += v;
      else            C[gm * ldc + gn] = v;
    }
  }
}

// ---------------------------------------------------------------------------
// Selective scan with fused dt_proj+softplus.
// Block = 16 channels x 16 states (256 threads, 4 waves). Grid = B*(ED/16)=128.
// Per 128-step chunk: stage dbc (all 48 cols) + xc in LDS; compute
// delta[t][e] = softplus(dbc[t][0:16] . dt_w[e] + dt_b[e]) in LDS; then scan:
// h = exp2(delta*Ap)*h + delta*x*B_n;  y = sum_n h*C_n + D*x.
// y written into the x_in half of XZ (stride 1024) for fused gating later.
// ---------------------------------------------------------------------------
__global__ __launch_bounds__(256) void scan_kernel(const float* __restrict__ xc,
                                                   const float* __restrict__ dbc,
                                                   const float* __restrict__ dt_w,
                                                   const float* __restrict__ dt_b,
                                                   const float* __restrict__ A_log,
                                                   const float* __restrict__ Dskip,
                                                   float* __restrict__ y) {
  constexpr int TCH = 128;
  __shared__ float sd[TCH][16], sx[TCH][16], sbc[TCH][48], sy[TCH][16];
  __shared__ float sw[16][17];   // dt_w rows for this block's 16 channels (+pad)
  __shared__ float sbias[16];
  const int b = blockIdx.x >> 5;
  const int e0 = (blockIdx.x & 31) * 16;
  const int tid = threadIdx.x;
  const int w = tid >> 6, lane = tid & 63;
  const int el = w * 4 + (lane >> 4);
  const int n = lane & 15;
  const int e = e0 + el;
  const float Ap = -expf(A_log[e * NST + n]) * LOG2E;
  const float dsk = Dskip[e];
  float h = 0.f;
  const size_t rowbase = (size_t)b * LSEQ;

  if (tid < 16 * 16) sw[tid >> 4][tid & 15] = dt_w[(e0 + (tid >> 4)) * 16 + (tid & 15)];
  if (tid < 16) sbias[tid] = dt_b[e0 + tid];
  __syncthreads();

  for (int c = 0; c < LSEQ / TCH; ++c) {
    const int t0 = c * TCH;
    #pragma unroll
    for (int i = 0; i < 8; ++i) {       // stage xc (128x16)
      int f = i * 256 + tid; int tt = f >> 4; int ee = f & 15;
      sx[tt][ee] = xc[(rowbase + t0 + tt) * ED + e0 + ee];
    }
    #pragma unroll
    for (int i = 0; i < 24; ++i) {      // stage dbc (128x48)
      int f = i * 256 + tid; int tt = f / 48; int cc = f % 48;
      sbc[tt][cc] = dbc[(rowbase + t0 + tt) * 48 + cc];
    }
    __syncthreads();
    #pragma unroll
    for (int i = 0; i < 8; ++i) {       // fused dt_proj + softplus (128x16)
      int f = i * 256 + tid; int tt = f >> 4; int ee = f & 15;
      float acc = sbias[ee];
      #pragma unroll
      for (int r = 0; r < 16; ++r) acc = fmaf(sbc[tt][r], sw[ee][r], acc);
      sd[tt][ee] = softplus_f(acc);
    }
    __syncthreads();
    #pragma unroll 4
    for (int t = 0; t < TCH; ++t) {
      float d = sd[t][el], x = sx[t][el];
      float bn = sbc[t][16 + n], cn = sbc[t][32 + n];
      float dA = exp2f(d * Ap);
      h = fmaf(dA, h, d * x * bn);
      float p = h * cn;
      p += __shfl_xor(p, 1);
      p += __shfl_xor(p, 2);
      p += __shfl_xor(p, 4);
      p += __shfl_xor(p, 8);
      if (n == 0) sy[t][el] = fmaf(dsk, x, p);
    }
    __syncthreads();
    #pragma unroll
    for (int i = 0; i < 8; ++i) {
      int f = i * 256 + tid; int tt = f >> 4; int ee = f & 15;
      y[(rowbase + t0 + tt) * 1024 + e0 + ee] = sy[tt][ee];
    }
    __syncthreads();
  }
}

// ---------------------------------------------------------------------------
extern "C" void kernel_launch(void* const* d_in, const int* in_sizes, int n_in,
                              void* d_out, int out_size, void* d_ws, size_t ws_size,
                              hipStream_t stream) {
  const float* x      = (const float*)d_in[0];
  const float* in_w   = (const float*)d_in[1];
  const float* conv_w = (const float*)d_in[2];
  const float* conv_b = (const float*)d_in[3];
  const float* xp_w   = (const float*)d_in[4];
  const float* dt_w   = (const float*)d_in[5];
  const float* dt_b   = (const float*)d_in[6];
  const float* A_log  = (const float*)d_in[7];
  const float* Dsk    = (const float*)d_in[8];
  const float* out_w  = (const float*)d_in[9];
  const float* norm_w = (const float*)d_in[10];
  float* out = (float*)d_out;

  // Workspace layout (floats). Total = 30,146,560 floats = ~115 MiB.
  // Guard: if the harness workspace is smaller, fail cleanly (absmax ~5.0
  // signature) instead of faulting the GPU.
  if (ws_size < 30146560ULL * 4ULL) return;
  float* ws  = (float*)d_ws;
  float* SEQ = ws;                  // 4,194,304   (B,L,D) residual stream
  float* XZ  = SEQ + 4194304;       // 16,777,216  (B,L,1024) [x_in | z]; y overwrites x_in
  float* XC  = XZ + 16777216;       // 8,388,608   (B,L,512) conv output
  float* DBC = XC + 8388608;        // 786,432     (B,L,48)
  float* TMP = XC;                  // alias: rmsnorm out, dead before conv writes XC

  // (B,D,L) -> (B,L,D)
  transpose_brc<<<dim3(LSEQ / 32, DM / 32, BSZ), dim3(32, 8), 0, stream>>>(x, SEQ, DM, LSEQ);

  for (int i = 0; i < 2; ++i) {
    rmsnorm_kernel<<<BSZ * LSEQ / 4, 256, 0, stream>>>(SEQ, norm_w + i * DM, TMP);
    // in_proj: (16384,256) x (1024,256)^T -> XZ (ldc 1024)
    gemm_nt<128, 64, 16, 8, 4, 0, 0><<<dim3(1024 / 64, 16384 / 128), 256, 0, stream>>>(
        TMP, in_w + (size_t)i * 1024 * 256, XZ, 16384, 1024, 256, 256, 256, 1024);
    conv_silu_kernel<<<BSZ * LSEQ * 128 / 256, 256, 0, stream>>>(
        XZ, conv_w + i * ED * 4, conv_b + i * ED, XC);
    // x_proj: (16384,512) x (48,512)^T -> DBC
    gemm_nt<128, 48, 16, 8, 3, 0, 0><<<dim3(1, 16384 / 128), 256, 0, stream>>>(
        XC, xp_w + (size_t)i * 48 * 512, DBC, 16384, 48, 512, 512, 512, 48);
    // fused dt_proj + softplus + selective scan
    scan_kernel<<<BSZ * 32, 256, 0, stream>>>(
        XC, DBC, dt_w + (size_t)i * ED * 16, dt_b + i * ED,
        A_log + (size_t)i * ED * NST, Dsk + i * ED, XZ);
    // out_proj on gated y*silu(z), accumulate into SEQ (residual)
    gemm_nt<128, 64, 16, 8, 4, 1, 2><<<dim3(256 / 64, 16384 / 128), 256, 0, stream>>>(
        XZ, out_w + (size_t)i * 256 * 512, SEQ, 16384, 256, 512, 1024, 512, 256);
  }

  // (B,L,D) -> (B,D,L)
  transpose_brc<<<dim3(DM / 32, LSEQ / 32, BSZ), dim3(32, 8), 0, stream>>>(SEQ, out, LSEQ, DM);
}

// Round 8
// 1258.412 us; speedup vs baseline: 2.1772x; 2.1772x over previous
//
#include <hip/hip_runtime.h>
#include <hip/hip_bf16.h>

// Sizes (fixed by the problem)
// B=4, D_MODEL=256, L=64*64=4096, D_INNER=512, D_STATE=16, DT_RANK=16, D_CONV=4
#define BSZ 4
#define DM 256
#define LSEQ 4096
#define ED 512
#define NST 16
#define LOG2E 1.44269504088896f

__device__ __forceinline__ float silu_f(float v) { return v / (1.f + expf(-v)); }
__device__ __forceinline__ float softplus_f(float v) { return v > 20.f ? v : log1pf(expf(v)); }

// ---------------------------------------------------------------------------
// Batched transpose: out[b][c][r] = in[b][r][c]   (in: (B,R,C))
// ---------------------------------------------------------------------------
__global__ __launch_bounds__(256) void transpose_brc(const float* __restrict__ in,
                                                     float* __restrict__ out,
                                                     int R, int C) {
  __shared__ float tile[32][33];
  int b = blockIdx.z;
  int r0 = blockIdx.y * 32, c0 = blockIdx.x * 32;
  int tx = threadIdx.x, ty = threadIdx.y;  // block (32,8)
  #pragma unroll
  for (int i = ty; i < 32; i += 8)
    tile[i][tx] = in[((size_t)b * R + r0 + i) * C + c0 + tx];
  __syncthreads();
  #pragma unroll
  for (int i = ty; i < 32; i += 8)
    out[((size_t)b * C + c0 + i) * R + r0 + tx] = tile[tx][i];
}

// ---------------------------------------------------------------------------
// RMSNorm over last dim (256). One wave per row, 4 rows per block.
// ---------------------------------------------------------------------------
__global__ __launch_bounds__(256) void rmsnorm_kernel(const float* __restrict__ in,
                                                      const float* __restrict__ w,
                                                      float* __restrict__ out) {
  int row = blockIdx.x * 4 + (threadIdx.x >> 6);
  int lane = threadIdx.x & 63;
  float4 v = *(const float4*)&in[(size_t)row * DM + lane * 4];
  float ss = v.x * v.x + v.y * v.y + v.z * v.z + v.w * v.w;
  #pragma unroll
  for (int off = 32; off; off >>= 1) ss += __shfl_xor(ss, off);
  float r = rsqrtf(ss * (1.f / DM) + 1e-5f);
  float4 wv = *(const float4*)&w[lane * 4];
  float4 o;
  o.x = v.x * r * wv.x; o.y = v.y * r * wv.y;
  o.z = v.z * r * wv.z; o.w = v.w * r * wv.w;
  *(float4*)&out[(size_t)row * DM + lane * 4] = o;
}

// ---------------------------------------------------------------------------
// Depthwise causal conv1d (K=4) + bias + SiLU.
// Input: x_in half of XZ (row stride 1024). Output: XC (B*L, 512).
// ---------------------------------------------------------------------------
__global__ __launch_bounds__(256) void conv_silu_kernel(const float* __restrict__ xz,
                                                        const float* __restrict__ cw,
                                                        const float* __restrict__ cb,
                                                        float* __restrict__ xc) {
  int idx = blockIdx.x * 256 + threadIdx.x;  // B*L*128
  int e4 = (idx & 127) * 4;
  int bt = idx >> 7;
  int t = bt & (LSEQ - 1);
  float wts[4][4];
  #pragma unroll
  for (int j = 0; j < 4; ++j) {
    float4 t4 = *(const float4*)&cw[(e4 + j) * 4];
    wts[j][0] = t4.x; wts[j][1] = t4.y; wts[j][2] = t4.z; wts[j][3] = t4.w;
  }
  float4 bv = *(const float4*)&cb[e4];
  float acc[4] = {bv.x, bv.y, bv.z, bv.w};
  #pragma unroll
  for (int k = 0; k < 4; ++k) {
    int tt = t - 3 + k;
    if (tt >= 0) {
      float4 xv = *(const float4*)&xz[((size_t)(bt + k - 3)) * 1024 + e4];
      acc[0] = fmaf(xv.x, wts[0][k], acc[0]);
      acc[1] = fmaf(xv.y, wts[1][k], acc[1]);
      acc[2] = fmaf(xv.z, wts[2][k], acc[2]);
      acc[3] = fmaf(xv.w, wts[3][k], acc[3]);
    }
  }
  float4 o;
  o.x = silu_f(acc[0]); o.y = silu_f(acc[1]);
  o.z = silu_f(acc[2]); o.w = silu_f(acc[3]);
  *(float4*)&xc[(size_t)bt * ED + e4] = o;
}

// ---------------------------------------------------------------------------
// Tiled fp32 GEMM, NT layout: C[m][n] = sum_k A[m][k] * Bw[n][k]
// AMODE 0: plain A (lda).  AMODE 1: gated A from XZ: y[m,k]*silu(z[m,k])
// EMODE 0: store.  EMODE 2: C += v (residual)
// ---------------------------------------------------------------------------
template <int BM, int BN, int BK, int TM, int TN, int AMODE, int EMODE>
__global__ __launch_bounds__(256) void gemm_nt(const float* __restrict__ A,
                                               const float* __restrict__ Bw,
                                               float* __restrict__ C,
                                               int M, int N, int K,
                                               int lda, int ldb, int ldc) {
  constexpr int TX = BN / TN, TY = BM / TM;
  static_assert(TX * TY == 256, "block must be 256 threads");
  __shared__ float As[BM][BK + 1];
  __shared__ float Bs[BN][BK + 1];
  const int tid = threadIdx.x;
  const int tx = tid % TX, ty = tid / TX;
  const int m0 = blockIdx.y * BM, n0 = blockIdx.x * BN;
  float acc[TM][TN] = {};
  constexpr int VPR = BK / 4;        // float4 per LDS row
  constexpr int RPP = 256 / VPR;     // rows per load pass
  const int lr = tid / VPR, lc = (tid % VPR) * 4;

  for (int k0 = 0; k0 < K; k0 += BK) {
    for (int r = lr; r < BM; r += RPP) {
      const size_t row = (size_t)(m0 + r);
      float4 v;
      if (AMODE == 0) {
        v = *(const float4*)&A[row * lda + k0 + lc];
      } else {
        float4 yv = *(const float4*)&A[row * 1024 + k0 + lc];
        float4 zv = *(const float4*)&A[row * 1024 + 512 + k0 + lc];
        v.x = yv.x * silu_f(zv.x); v.y = yv.y * silu_f(zv.y);
        v.z = yv.z * silu_f(zv.z); v.w = yv.w * silu_f(zv.w);
      }
      As[r][lc] = v.x; As[r][lc + 1] = v.y; As[r][lc + 2] = v.z; As[r][lc + 3] = v.w;
    }
    for (int r = lr; r < BN; r += RPP) {
      float4 v = *(const float4*)&Bw[(size_t)(n0 + r) * ldb + k0 + lc];
      Bs[r][lc] = v.x; Bs[r][lc + 1] = v.y; Bs[r][lc + 2] = v.z; Bs[r][lc + 3] = v.w;
    }
    __syncthreads();
    #pragma unroll
    for (int kk = 0; kk < BK; ++kk) {
      float a[TM], bb[TN];
      #pragma unroll
      for (int i = 0; i < TM; ++i) a[i] = As[ty * TM + i][kk];
      #pragma unroll
      for (int j = 0; j < TN; ++j) bb[j] = Bs[tx * TN + j][kk];
      #pragma unroll
      for (int i = 0; i < TM; ++i)
        #pragma unroll
        for (int j = 0; j < TN; ++j)
          acc[i][j] = fmaf(a[i], bb[j], acc[i][j]);
    }
    __syncthreads();
  }

  #pragma unroll
  for (int i = 0; i < TM; ++i) {
    const size_t gm = (size_t)m0 + ty * TM + i;
    #pragma unroll
    for (int j = 0; j < TN; ++j) {
      const int gn = n0 + tx * TN + j;
      float v = acc[i][j];
      if (EMODE == 2) C[gm * ldc + gn] += v;
      else            C[gm * ldc + gn] = v;
    }
  }
}

// ---------------------------------------------------------------------------
// Two-pass segmented selective scan with fused dt_proj+softplus.
// Diagonal-affine recurrence: over a segment, h_end = A_seg*h_start + B_seg
// with A_seg[n] = exp2(Ap[n] * sum(delta)) -- so segments parallelize.
// Block = 256 threads = 8 channels x 32 segments of 128 steps. Each thread
// holds all 16 states in registers (no cross-lane reduce; y = 16 in-reg fma).
// Pass A: per-segment scan from h=0 -> (B_seg, sum_delta) in LDS.
// Combine: 128 threads (c,n) fold 32 segments -> h_start per segment in LDS.
// Pass B: replay with h_start, emit y = sum_n h*C + D*x into XZ's x_in half.
// Grid = (BSZ, ED/8) = 256 blocks.
// ---------------------------------------------------------------------------
__global__ __launch_bounds__(256) void scan2_kernel(const float* __restrict__ xc,
                                                    const float* __restrict__ dbc,
                                                    const float* __restrict__ dt_w,
                                                    const float* __restrict__ dt_b,
                                                    const float* __restrict__ A_log,
                                                    const float* __restrict__ Dskip,
                                                    float* __restrict__ y) {
  constexpr int NSEG = 32, TSEG = LSEQ / NSEG;  // 32 segments x 128 steps
  __shared__ float lB[8][NSEG][16];   // 16 KB: B_seg, then h_start
  __shared__ float lsum[8][NSEG];     // sum of delta per (c,s)
  const int b = blockIdx.x;
  const int e0 = blockIdx.y * 8;
  const int tid = threadIdx.x;
  const int c = tid & 7, s = tid >> 3;
  const int e = e0 + c;

  // Per-thread constants: dt_proj row, A', bias, D_skip.
  float w[16], Ap[16];
  #pragma unroll
  for (int i = 0; i < 4; ++i) {
    float4 t4 = *(const float4*)&dt_w[e * 16 + i * 4];
    w[i * 4] = t4.x; w[i * 4 + 1] = t4.y; w[i * 4 + 2] = t4.z; w[i * 4 + 3] = t4.w;
  }
  #pragma unroll
  for (int n = 0; n < 16; ++n) Ap[n] = -expf(A_log[e * 16 + n]) * LOG2E;
  const float bias = dt_b[e];
  const float dsk = Dskip[e];
  const size_t r0 = (size_t)b * LSEQ + (size_t)s * TSEG;  // global row of segment start

  float h[16];
  #pragma unroll
  for (int n = 0; n < 16; ++n) h[n] = 0.f;
  float sumd = 0.f;

  // ---- pass A: segment scan from h=0; record B_seg + sum(delta) ----
  #pragma unroll 2
  for (int t = 0; t < TSEG; ++t) {
    const float* dr = &dbc[(r0 + t) * 48];
    float dl = bias;
    float Bv[16];
    #pragma unroll
    for (int i = 0; i < 4; ++i) {
      float4 dv = *(const float4*)&dr[i * 4];
      dl = fmaf(dv.x, w[i * 4], dl);     dl = fmaf(dv.y, w[i * 4 + 1], dl);
      dl = fmaf(dv.z, w[i * 4 + 2], dl); dl = fmaf(dv.w, w[i * 4 + 3], dl);
      float4 bv = *(const float4*)&dr[16 + i * 4];
      Bv[i * 4] = bv.x; Bv[i * 4 + 1] = bv.y; Bv[i * 4 + 2] = bv.z; Bv[i * 4 + 3] = bv.w;
    }
    dl = softplus_f(dl);
    sumd += dl;
    float x = xc[(r0 + t) * ED + e];
    float dx = dl * x;
    #pragma unroll
    for (int n = 0; n < 16; ++n)
      h[n] = fmaf(exp2f(dl * Ap[n]), h[n], dx * Bv[n]);
  }
  #pragma unroll
  for (int n = 0; n < 16; ++n) lB[c][s][n] = h[n];
  lsum[c][s] = sumd;
  __syncthreads();

  // ---- combine: thread (c,n) folds segments sequentially ----
  if (tid < 128) {
    const int cc = tid >> 4, nn = tid & 15;
    const float Apn = -expf(A_log[(e0 + cc) * 16 + nn]) * LOG2E;
    float H = 0.f;
    for (int ss = 0; ss < NSEG; ++ss) {
      float Bs = lB[cc][ss][nn];
      lB[cc][ss][nn] = H;               // h_start for segment ss
      H = fmaf(exp2f(Apn * lsum[cc][ss]), H, Bs);
    }
  }
  __syncthreads();

  // ---- pass B: replay with h_start, emit y ----
  #pragma unroll
  for (int n = 0; n < 16; ++n) h[n] = lB[c][s][n];
  #pragma unroll 2
  for (int t = 0; t < TSEG; ++t) {
    const float* dr = &dbc[(r0 + t) * 48];
    float dl = bias;
    float Bv[16], Cv[16];
    #pragma unroll
    for (int i = 0; i < 4; ++i) {
      float4 dv = *(const float4*)&dr[i * 4];
      dl = fmaf(dv.x, w[i * 4], dl);     dl = fmaf(dv.y, w[i * 4 + 1], dl);
      dl = fmaf(dv.z, w[i * 4 + 2], dl); dl = fmaf(dv.w, w[i * 4 + 3], dl);
      float4 bv = *(const float4*)&dr[16 + i * 4];
      Bv[i * 4] = bv.x; Bv[i * 4 + 1] = bv.y; Bv[i * 4 + 2] = bv.z; Bv[i * 4 + 3] = bv.w;
      float4 cv = *(const float4*)&dr[32 + i * 4];
      Cv[i * 4] = cv.x; Cv[i * 4 + 1] = cv.y; Cv[i * 4 + 2] = cv.z; Cv[i * 4 + 3] = cv.w;
    }
    dl = softplus_f(dl);
    float x = xc[(r0 + t) * ED + e];
    float dx = dl * x;
    float acc = 0.f;
    #pragma unroll
    for (int n = 0; n < 16; ++n) {
      h[n] = fmaf(exp2f(dl * Ap[n]), h[n], dx * Bv[n]);
      acc = fmaf(h[n], Cv[n], acc);
    }
    y[(r0 + t) * 1024 + e] = fmaf(dsk, x, acc);
  }
}

// ---------------------------------------------------------------------------
extern "C" void kernel_launch(void* const* d_in, const int* in_sizes, int n_in,
                              void* d_out, int out_size, void* d_ws, size_t ws_size,
                              hipStream_t stream) {
  const float* x      = (const float*)d_in[0];
  const float* in_w   = (const float*)d_in[1];
  const float* conv_w = (const float*)d_in[2];
  const float* conv_b = (const float*)d_in[3];
  const float* xp_w   = (const float*)d_in[4];
  const float* dt_w   = (const float*)d_in[5];
  const float* dt_b   = (const float*)d_in[6];
  const float* A_log  = (const float*)d_in[7];
  const float* Dsk    = (const float*)d_in[8];
  const float* out_w  = (const float*)d_in[9];
  const float* norm_w = (const float*)d_in[10];
  float* out = (float*)d_out;

  // Workspace layout (floats). Total = 30,146,560 floats = ~115 MiB.
  // Guard: if the harness workspace is smaller, fail cleanly (absmax ~5.0
  // signature) instead of faulting the GPU.  (Round 7: ws_size >= this.)
  if (ws_size < 30146560ULL * 4ULL) return;
  float* ws  = (float*)d_ws;
  float* SEQ = ws;                  // 4,194,304   (B,L,D) residual stream
  float* XZ  = SEQ + 4194304;       // 16,777,216  (B,L,1024) [x_in | z]; y overwrites x_in
  float* XC  = XZ + 16777216;       // 8,388,608   (B,L,512) conv output
  float* DBC = XC + 8388608;        // 786,432     (B,L,48)
  float* TMP = XC;                  // alias: rmsnorm out, dead before conv writes XC

  // (B,D,L) -> (B,L,D)
  transpose_brc<<<dim3(LSEQ / 32, DM / 32, BSZ), dim3(32, 8), 0, stream>>>(x, SEQ, DM, LSEQ);

  for (int i = 0; i < 2; ++i) {
    rmsnorm_kernel<<<BSZ * LSEQ / 4, 256, 0, stream>>>(SEQ, norm_w + i * DM, TMP);
    // in_proj: (16384,256) x (1024,256)^T -> XZ (ldc 1024)
    gemm_nt<128, 64, 16, 8, 4, 0, 0><<<dim3(1024 / 64, 16384 / 128), 256, 0, stream>>>(
        TMP, in_w + (size_t)i * 1024 * 256, XZ, 16384, 1024, 256, 256, 256, 1024);
    conv_silu_kernel<<<BSZ * LSEQ * 128 / 256, 256, 0, stream>>>(
        XZ, conv_w + i * ED * 4, conv_b + i * ED, XC);
    // x_proj: (16384,512) x (48,512)^T -> DBC
    gemm_nt<128, 48, 16, 8, 3, 0, 0><<<dim3(1, 16384 / 128), 256, 0, stream>>>(
        XC, xp_w + (size_t)i * 48 * 512, DBC, 16384, 48, 512, 512, 512, 48);
    // fused dt_proj + softplus + two-pass segmented selective scan
    scan2_kernel<<<dim3(BSZ, ED / 8), 256, 0, stream>>>(
        XC, DBC, dt_w + (size_t)i * ED * 16, dt_b + i * ED,
        A_log + (size_t)i * ED * NST, Dsk + i * ED, XZ);
    // out_proj on gated y*silu(z), accumulate into SEQ (residual)
    gemm_nt<128, 64, 16, 8, 4, 1, 2><<<dim3(256 / 64, 16384 / 128), 256, 0, stream>>>(
        XZ, out_w + (size_t)i * 256 * 512, SEQ, 16384, 256, 512, 1024, 512, 256);
  }

  // (B,L,D) -> (B,D,L)
  transpose_brc<<<dim3(DM / 32, LSEQ / 32, BSZ), dim3(32, 8), 0, stream>>>(SEQ, out, LSEQ, DM);
}

// Round 11
// 1054.950 us; speedup vs baseline: 2.5971x; 1.1929x over previous
//
#include <hip/hip_runtime.h>
#include <hip/hip_bf16.h>

// Sizes (fixed by the problem)
// B=4, D_MODEL=256, L=64*64=4096, D_INNER=512, D_STATE=16, DT_RANK=16, D_CONV=4
#define BSZ 4
#define DM 256
#define LSEQ 4096
#define ED 512
#define NST 16
#define LOG2E 1.44269504088896f

__device__ __forceinline__ float silu_f(float v) { return v / (1.f + expf(-v)); }
__device__ __forceinline__ float softplus_f(float v) { return v > 20.f ? v : log1pf(expf(v)); }

// ---------------------------------------------------------------------------
// Batched transpose: out[b][c][r] = in[b][r][c]   (in: (B,R,C))
// ---------------------------------------------------------------------------
__global__ __launch_bounds__(256) void transpose_brc(const float* __restrict__ in,
                                                     float* __restrict__ out,
                                                     int R, int C) {
  __shared__ float tile[32][33];
  int b = blockIdx.z;
  int r0 = blockIdx.y * 32, c0 = blockIdx.x * 32;
  int tx = threadIdx.x, ty = threadIdx.y;  // block (32,8)
  #pragma unroll
  for (int i = ty; i < 32; i += 8)
    tile[i][tx] = in[((size_t)b * R + r0 + i) * C + c0 + tx];
  __syncthreads();
  #pragma unroll
  for (int i = ty; i < 32; i += 8)
    out[((size_t)b * C + c0 + i) * R + r0 + tx] = tile[tx][i];
}

// ---------------------------------------------------------------------------
// RMSNorm over last dim (256). One wave per row, 4 rows per block.
// ---------------------------------------------------------------------------
__global__ __launch_bounds__(256) void rmsnorm_kernel(const float* __restrict__ in,
                                                      const float* __restrict__ w,
                                                      float* __restrict__ out) {
  int row = blockIdx.x * 4 + (threadIdx.x >> 6);
  int lane = threadIdx.x & 63;
  float4 v = *(const float4*)&in[(size_t)row * DM + lane * 4];
  float ss = v.x * v.x + v.y * v.y + v.z * v.z + v.w * v.w;
  #pragma unroll
  for (int off = 32; off; off >>= 1) ss += __shfl_xor(ss, off);
  float r = rsqrtf(ss * (1.f / DM) + 1e-5f);
  float4 wv = *(const float4*)&w[lane * 4];
  float4 o;
  o.x = v.x * r * wv.x; o.y = v.y * r * wv.y;
  o.z = v.z * r * wv.z; o.w = v.w * r * wv.w;
  *(float4*)&out[(size_t)row * DM + lane * 4] = o;
}

// ---------------------------------------------------------------------------
// Depthwise causal conv1d (K=4) + bias + SiLU.
// Input: x_in half of XZ (row stride 1024). Output: XC (B*L, 512).
// ---------------------------------------------------------------------------
__global__ __launch_bounds__(256) void conv_silu_kernel(const float* __restrict__ xz,
                                                        const float* __restrict__ cw,
                                                        const float* __restrict__ cb,
                                                        float* __restrict__ xc) {
  int idx = blockIdx.x * 256 + threadIdx.x;  // B*L*128
  int e4 = (idx & 127) * 4;
  int bt = idx >> 7;
  int t = bt & (LSEQ - 1);
  float wts[4][4];
  #pragma unroll
  for (int j = 0; j < 4; ++j) {
    float4 t4 = *(const float4*)&cw[(e4 + j) * 4];
    wts[j][0] = t4.x; wts[j][1] = t4.y; wts[j][2] = t4.z; wts[j][3] = t4.w;
  }
  float4 bv = *(const float4*)&cb[e4];
  float acc[4] = {bv.x, bv.y, bv.z, bv.w};
  #pragma unroll
  for (int k = 0; k < 4; ++k) {
    int tt = t - 3 + k;
    if (tt >= 0) {
      float4 xv = *(const float4*)&xz[((size_t)(bt + k - 3)) * 1024 + e4];
      acc[0] = fmaf(xv.x, wts[0][k], acc[0]);
      acc[1] = fmaf(xv.y, wts[1][k], acc[1]);
      acc[2] = fmaf(xv.z, wts[2][k], acc[2]);
      acc[3] = fmaf(xv.w, wts[3][k], acc[3]);
    }
  }
  float4 o;
  o.x = silu_f(acc[0]); o.y = silu_f(acc[1]);
  o.z = silu_f(acc[2]); o.w = silu_f(acc[3]);
  *(float4*)&xc[(size_t)bt * ED + e4] = o;
}

// ---------------------------------------------------------------------------
// Tiled fp32 GEMM, NT layout: C[m][n] = sum_k A[m][k] * Bw[n][k]
// AMODE 0: plain A (lda).  AMODE 1: gated A from XZ: y[m,k]*silu(z[m,k])
// EMODE 0: store.  EMODE 2: C += v (residual)
// ---------------------------------------------------------------------------
template <int BM, int BN, int BK, int TM, int TN, int AMODE, int EMODE>
__global__ __launch_bounds__(256) void gemm_nt(const float* __restrict__ A,
                                               const float* __restrict__ Bw,
                                               float* __restrict__ C,
                                               int M, int N, int K,
                                               int lda, int ldb, int ldc) {
  constexpr int TX = BN / TN, TY = BM / TM;
  static_assert(TX * TY == 256, "block must be 256 threads");
  __shared__ float As[BM][BK + 1];
  __shared__ float Bs[BN][BK + 1];
  const int tid = threadIdx.x;
  const int tx = tid % TX, ty = tid / TX;
  const int m0 = blockIdx.y * BM, n0 = blockIdx.x * BN;
  float acc[TM][TN] = {};
  constexpr int VPR = BK / 4;        // float4 per LDS row
  constexpr int RPP = 256 / VPR;     // rows per load pass
  const int lr = tid / VPR, lc = (tid % VPR) * 4;

  for (int k0 = 0; k0 < K; k0 += BK) {
    for (int r = lr; r < BM; r += RPP) {
      const size_t row = (size_t)(m0 + r);
      float4 v;
      if (AMODE == 0) {
        v = *(const float4*)&A[row * lda + k0 + lc];
      } else {
        float4 yv = *(const float4*)&A[row * 1024 + k0 + lc];
        float4 zv = *(const float4*)&A[row * 1024 + 512 + k0 + lc];
        v.x = yv.x * silu_f(zv.x); v.y = yv.y * silu_f(zv.y);
        v.z = yv.z * silu_f(zv.z); v.w = yv.w * silu_f(zv.w);
      }
      As[r][lc] = v.x; As[r][lc + 1] = v.y; As[r][lc + 2] = v.z; As[r][lc + 3] = v.w;
    }
    for (int r = lr; r < BN; r += RPP) {
      float4 v = *(const float4*)&Bw[(size_t)(n0 + r) * ldb + k0 + lc];
      Bs[r][lc] = v.x; Bs[r][lc + 1] = v.y; Bs[r][lc + 2] = v.z; Bs[r][lc + 3] = v.w;
    }
    __syncthreads();
    #pragma unroll
    for (int kk = 0; kk < BK; ++kk) {
      float a[TM], bb[TN];
      #pragma unroll
      for (int i = 0; i < TM; ++i) a[i] = As[ty * TM + i][kk];
      #pragma unroll
      for (int j = 0; j < TN; ++j) bb[j] = Bs[tx * TN + j][kk];
      #pragma unroll
      for (int i = 0; i < TM; ++i)
        #pragma unroll
        for (int j = 0; j < TN; ++j)
          acc[i][j] = fmaf(a[i], bb[j], acc[i][j]);
    }
    __syncthreads();
  }

  #pragma unroll
  for (int i = 0; i < TM; ++i) {
    const size_t gm = (size_t)m0 + ty * TM + i;
    #pragma unroll
    for (int j = 0; j < TN; ++j) {
      const int gn = n0 + tx * TN + j;
      float v = acc[i][j];
      if (EMODE == 2) C[gm * ldc + gn] += v;
      else            C[gm * ldc + gn] = v;
    }
  }
}

// ---------------------------------------------------------------------------
// Two-pass segmented selective scan, v3.
// Block = 256 threads = 4 channels x 64 segments of 64 steps; grid (B, ED/4)
// = 512 blocks -> 2 blocks/CU, 2 waves/SIMD (v2 was 1/SIMD, VALUBusy 55%).
// Trans reduction: A_log[e][n] = log(n+1) (problem setup), so
// dA_n = exp(-delta*(n+1)) = a^(n+1), a = exp2(delta*Ap[0]) -- 1 trans + 15
// muls instead of 16 exp2 per step. Runtime-checked with generic fallback.
// ---------------------------------------------------------------------------
__global__ __launch_bounds__(256) void scan3_kernel(const float* __restrict__ xc,
                                                    const float* __restrict__ dbc,
                                                    const float* __restrict__ dt_w,
                                                    const float* __restrict__ dt_b,
                                                    const float* __restrict__ A_log,
                                                    const float* __restrict__ Dskip,
                                                    float* __restrict__ y) {
  constexpr int NSEG = 64, TSEG = LSEQ / NSEG;  // 64 segments x 64 steps
  __shared__ float lB[4][NSEG][16];   // 16 KB: B_seg, then h_start
  __shared__ float lsum[4][NSEG];     // sum of delta per (c,s)
  const int b = blockIdx.x;
  const int e0 = blockIdx.y * 4;
  const int tid = threadIdx.x;
  const int c = tid & 3, s = tid >> 2;
  const int e = e0 + c;

  // Per-thread constants: dt_proj row, A', bias, D_skip.
  float w[16], Ap[16];
  #pragma unroll
  for (int i = 0; i < 4; ++i) {
    float4 t4 = *(const float4*)&dt_w[e * 16 + i * 4];
    w[i * 4] = t4.x; w[i * 4 + 1] = t4.y; w[i * 4 + 2] = t4.z; w[i * 4 + 3] = t4.w;
  }
  #pragma unroll
  for (int n = 0; n < 16; ++n) Ap[n] = -expf(A_log[e * 16 + n]) * LOG2E;
  bool structured = true;
  #pragma unroll
  for (int n = 1; n < 16; ++n)
    structured = structured && (fabsf(Ap[n] - (n + 1) * Ap[0]) <= 1e-3f * (n + 1));
  const float bias = dt_b[e];
  const float dsk = Dskip[e];
  const size_t r0 = (size_t)b * LSEQ + (size_t)s * TSEG;  // segment start row

  // dA_n via binary power tree (structured) or generic exp2 (fallback).
  auto calc_dA = [&](float dl, float* dA) {
    if (structured) {
      float a = exp2f(dl * Ap[0]);
      float p2 = a * a, p4, p8;
      p4 = p2 * p2; p8 = p4 * p4;
      dA[0] = a;          dA[1] = p2;         dA[2] = p2 * a;     dA[3] = p4;
      dA[4] = p4 * a;     dA[5] = p4 * p2;    dA[6] = p4 * dA[2]; dA[7] = p8;
      dA[8] = p8 * a;     dA[9] = p8 * p2;    dA[10] = p8 * dA[2]; dA[11] = p8 * p4;
      dA[12] = p8 * dA[4]; dA[13] = p8 * dA[5]; dA[14] = p8 * dA[6]; dA[15] = p8 * p8;
    } else {
      #pragma unroll
      for (int n = 0; n < 16; ++n) dA[n] = exp2f(dl * Ap[n]);
    }
  };

  float h[16];
  #pragma unroll
  for (int n = 0; n < 16; ++n) h[n] = 0.f;
  float sumd = 0.f;

  // ---- pass A: segment scan from h=0; record B_seg + sum(delta) ----
  #pragma unroll 2
  for (int t = 0; t < TSEG; ++t) {
    const float* dr = &dbc[(r0 + t) * 48];
    float dl = bias;
    float Bv[16];
    #pragma unroll
    for (int i = 0; i < 4; ++i) {
      float4 dv = *(const float4*)&dr[i * 4];
      dl = fmaf(dv.x, w[i * 4], dl);     dl = fmaf(dv.y, w[i * 4 + 1], dl);
      dl = fmaf(dv.z, w[i * 4 + 2], dl); dl = fmaf(dv.w, w[i * 4 + 3], dl);
      float4 bv = *(const float4*)&dr[16 + i * 4];
      Bv[i * 4] = bv.x; Bv[i * 4 + 1] = bv.y; Bv[i * 4 + 2] = bv.z; Bv[i * 4 + 3] = bv.w;
    }
    dl = softplus_f(dl);
    sumd += dl;
    float x = xc[(r0 + t) * ED + e];
    float dx = dl * x;
    float dA[16];
    calc_dA(dl, dA);
    #pragma unroll
    for (int n = 0; n < 16; ++n)
      h[n] = fmaf(dA[n], h[n], dx * Bv[n]);
  }
  #pragma unroll
  for (int n = 0; n < 16; ++n) lB[c][s][n] = h[n];
  lsum[c][s] = sumd;
  __syncthreads();

  // ---- combine: thread (c,n) folds 64 segments sequentially ----
  if (tid < 64) {
    const int cc = tid >> 4, nn = tid & 15;
    const float Apn = -expf(A_log[(e0 + cc) * 16 + nn]) * LOG2E;
    float H = 0.f;
    for (int ss = 0; ss < NSEG; ++ss) {
      float Bs = lB[cc][ss][nn];
      lB[cc][ss][nn] = H;               // h_start for segment ss
      H = fmaf(exp2f(Apn * lsum[cc][ss]), H, Bs);
    }
  }
  __syncthreads();

  // ---- pass B: replay with h_start, emit y ----
  #pragma unroll
  for (int n = 0; n < 16; ++n) h[n] = lB[c][s][n];
  #pragma unroll 2
  for (int t = 0; t < TSEG; ++t) {
    const float* dr = &dbc[(r0 + t) * 48];
    float dl = bias;
    float Bv[16], Cv[16];
    #pragma unroll
    for (int i = 0; i < 4; ++i) {
      float4 dv = *(const float4*)&dr[i * 4];
      dl = fmaf(dv.x, w[i * 4], dl);     dl = fmaf(dv.y, w[i * 4 + 1], dl);
      dl = fmaf(dv.z, w[i * 4 + 2], dl); dl = fmaf(dv.w, w[i * 4 + 3], dl);
      float4 bv = *(const float4*)&dr[16 + i * 4];
      Bv[i * 4] = bv.x; Bv[i * 4 + 1] = bv.y; Bv[i * 4 + 2] = bv.z; Bv[i * 4 + 3] = bv.w;
      float4 cv = *(const float4*)&dr[32 + i * 4];
      Cv[i * 4] = cv.x; Cv[i * 4 + 1] = cv.y; Cv[i * 4 + 2] = cv.z; Cv[i * 4 + 3] = cv.w;
    }
    dl = softplus_f(dl);
    float x = xc[(r0 + t) * ED + e];
    float dx = dl * x;
    float dA[16];
    calc_dA(dl, dA);
    float acc = 0.f;
    #pragma unroll
    for (int n = 0; n < 16; ++n) {
      h[n] = fmaf(dA[n], h[n], dx * Bv[n]);
      acc = fmaf(h[n], Cv[n], acc);
    }
    y[(r0 + t) * 1024 + e] = fmaf(dsk, x, acc);
  }
}

// ---------------------------------------------------------------------------
extern "C" void kernel_launch(void* const* d_in, const int* in_sizes, int n_in,
                              void* d_out, int out_size, void* d_ws, size_t ws_size,
                              hipStream_t stream) {
  const float* x      = (const float*)d_in[0];
  const float* in_w   = (const float*)d_in[1];
  const float* conv_w = (const float*)d_in[2];
  const float* conv_b = (const float*)d_in[3];
  const float* xp_w   = (const float*)d_in[4];
  const float* dt_w   = (const float*)d_in[5];
  const float* dt_b   = (const float*)d_in[6];
  const float* A_log  = (const float*)d_in[7];
  const float* Dsk    = (const float*)d_in[8];
  const float* out_w  = (const float*)d_in[9];
  const float* norm_w = (const float*)d_in[10];
  float* out = (float*)d_out;

  // Workspace layout (floats). Total = 30,146,560 floats = ~115 MiB.
  // Guard: verified sufficient in Round 7.
  if (ws_size < 30146560ULL * 4ULL) return;
  float* ws  = (float*)d_ws;
  float* SEQ = ws;                  // 4,194,304   (B,L,D) residual stream
  float* XZ  = SEQ + 4194304;       // 16,777,216  (B,L,1024) [x_in | z]; y overwrites x_in
  float* XC  = XZ + 16777216;       // 8,388,608   (B,L,512) conv output
  float* DBC = XC + 8388608;        // 786,432     (B,L,48)
  float* TMP = XC;                  // alias: rmsnorm out, dead before conv writes XC

  // (B,D,L) -> (B,L,D)
  transpose_brc<<<dim3(LSEQ / 32, DM / 32, BSZ), dim3(32, 8), 0, stream>>>(x, SEQ, DM, LSEQ);

  for (int i = 0; i < 2; ++i) {
    rmsnorm_kernel<<<BSZ * LSEQ / 4, 256, 0, stream>>>(SEQ, norm_w + i * DM, TMP);
    // in_proj: (16384,256) x (1024,256)^T -> XZ (ldc 1024)
    gemm_nt<128, 64, 16, 8, 4, 0, 0><<<dim3(1024 / 64, 16384 / 128), 256, 0, stream>>>(
        TMP, in_w + (size_t)i * 1024 * 256, XZ, 16384, 1024, 256, 256, 256, 1024);
    conv_silu_kernel<<<BSZ * LSEQ * 128 / 256, 256, 0, stream>>>(
        XZ, conv_w + i * ED * 4, conv_b + i * ED, XC);
    // x_proj: (16384,512) x (48,512)^T -> DBC
    gemm_nt<128, 48, 16, 8, 3, 0, 0><<<dim3(1, 16384 / 128), 256, 0, stream>>>(
        XC, xp_w + (size_t)i * 48 * 512, DBC, 16384, 48, 512, 512, 512, 48);
    // fused dt_proj + softplus + two-pass segmented selective scan (v3)
    scan3_kernel<<<dim3(BSZ, ED / 4), 256, 0, stream>>>(
        XC, DBC, dt_w + (size_t)i * ED * 16, dt_b + i * ED,
        A_log + (size_t)i * ED * NST, Dsk + i * ED, XZ);
    // out_proj on gated y*silu(z), accumulate into SEQ (residual)
    gemm_nt<128, 64, 16, 8, 4, 1, 2><<<dim3(256 / 64, 16384 / 128), 256, 0, stream>>>(
        XZ, out_w + (size_t)i * 256 * 512, SEQ, 16384, 256, 512, 1024, 512, 256);
  }

  // (B,L,D) -> (B,D,L)
  transpose_brc<<<dim3(DM / 32, LSEQ / 32, BSZ), dim3(32, 8), 0, stream>>>(SEQ, out, LSEQ, DM);
}

// Round 13
// 729.216 us; speedup vs baseline: 3.7572x; 1.4467x over previous
//
#include <hip/hip_runtime.h>
#include <hip/hip_bf16.h>

// Sizes (fixed by the problem)
// B=4, D_MODEL=256, L=64*64=4096, D_INNER=512, D_STATE=16, DT_RANK=16, D_CONV=4
#define BSZ 4
#define DM 256
#define LSEQ 4096
#define ED 512
#define NST 16
#define LOG2E 1.44269504088896f

__device__ __forceinline__ float silu_f(float v) { return v / (1.f + expf(-v)); }
__device__ __forceinline__ float softplus_f(float v) { return v > 20.f ? v : log1pf(expf(v)); }

typedef __attribute__((ext_vector_type(8))) short bf16x8;
typedef __attribute__((ext_vector_type(8))) unsigned short u16x8;
typedef __attribute__((ext_vector_type(4))) float f32x4;

__device__ __forceinline__ unsigned short f2bf(float f) {
  unsigned u = __builtin_bit_cast(unsigned, f);
  u += 0x7fff + ((u >> 16) & 1);            // round-to-nearest-even
  return (unsigned short)(u >> 16);
}

// ---------------------------------------------------------------------------
// Batched transpose: out[b][c][r] = in[b][r][c]   (in: (B,R,C))
// ---------------------------------------------------------------------------
__global__ __launch_bounds__(256) void transpose_brc(const float* __restrict__ in,
                                                     float* __restrict__ out,
                                                     int R, int C) {
  __shared__ float tile[32][33];
  int b = blockIdx.z;
  int r0 = blockIdx.y * 32, c0 = blockIdx.x * 32;
  int tx = threadIdx.x, ty = threadIdx.y;  // block (32,8)
  #pragma unroll
  for (int i = ty; i < 32; i += 8)
    tile[i][tx] = in[((size_t)b * R + r0 + i) * C + c0 + tx];
  __syncthreads();
  #pragma unroll
  for (int i = ty; i < 32; i += 8)
    out[((size_t)b * C + c0 + i) * R + r0 + tx] = tile[tx][i];
}

// ---------------------------------------------------------------------------
// RMSNorm over last dim (256). One wave per row, 4 rows per block.
// ---------------------------------------------------------------------------
__global__ __launch_bounds__(256) void rmsnorm_kernel(const float* __restrict__ in,
                                                      const float* __restrict__ w,
                                                      float* __restrict__ out) {
  int row = blockIdx.x * 4 + (threadIdx.x >> 6);
  int lane = threadIdx.x & 63;
  float4 v = *(const float4*)&in[(size_t)row * DM + lane * 4];
  float ss = v.x * v.x + v.y * v.y + v.z * v.z + v.w * v.w;
  #pragma unroll
  for (int off = 32; off; off >>= 1) ss += __shfl_xor(ss, off);
  float r = rsqrtf(ss * (1.f / DM) + 1e-5f);
  float4 wv = *(const float4*)&w[lane * 4];
  float4 o;
  o.x = v.x * r * wv.x; o.y = v.y * r * wv.y;
  o.z = v.z * r * wv.z; o.w = v.w * r * wv.w;
  *(float4*)&out[(size_t)row * DM + lane * 4] = o;
}

// ---------------------------------------------------------------------------
// Depthwise causal conv1d (K=4) + bias + SiLU.
// Input: x_in half of XZ (row stride 1024). Output: XC (B*L, 512).
// ---------------------------------------------------------------------------
__global__ __launch_bounds__(256) void conv_silu_kernel(const float* __restrict__ xz,
                                                        const float* __restrict__ cw,
                                                        const float* __restrict__ cb,
                                                        float* __restrict__ xc) {
  int idx = blockIdx.x * 256 + threadIdx.x;  // B*L*128
  int e4 = (idx & 127) * 4;
  int bt = idx >> 7;
  int t = bt & (LSEQ - 1);
  float wts[4][4];
  #pragma unroll
  for (int j = 0; j < 4; ++j) {
    float4 t4 = *(const float4*)&cw[(e4 + j) * 4];
    wts[j][0] = t4.x; wts[j][1] = t4.y; wts[j][2] = t4.z; wts[j][3] = t4.w;
  }
  float4 bv = *(const float4*)&cb[e4];
  float acc[4] = {bv.x, bv.y, bv.z, bv.w};
  #pragma unroll
  for (int k = 0; k < 4; ++k) {
    int tt = t - 3 + k;
    if (tt >= 0) {
      float4 xv = *(const float4*)&xz[((size_t)(bt + k - 3)) * 1024 + e4];
      acc[0] = fmaf(xv.x, wts[0][k], acc[0]);
      acc[1] = fmaf(xv.y, wts[1][k], acc[1]);
      acc[2] = fmaf(xv.z, wts[2][k], acc[2]);
      acc[3] = fmaf(xv.w, wts[3][k], acc[3]);
    }
  }
  float4 o;
  o.x = silu_f(acc[0]); o.y = silu_f(acc[1]);
  o.z = silu_f(acc[2]); o.w = silu_f(acc[3]);
  *(float4*)&xc[(size_t)bt * ED + e4] = o;
}

// ---------------------------------------------------------------------------
// Tiled fp32 GEMM, NT layout (kept for x_proj: N=48 doesn't tile to 64).
// ---------------------------------------------------------------------------
template <int BM, int BN, int BK, int TM, int TN, int AMODE, int EMODE>
__global__ __launch_bounds__(256) void gemm_nt(const float* __restrict__ A,
                                               const float* __restrict__ Bw,
                                               float* __restrict__ C,
                                               int M, int N, int K,
                                               int lda, int ldb, int ldc) {
  constexpr int TX = BN / TN, TY = BM / TM;
  static_assert(TX * TY == 256, "block must be 256 threads");
  __shared__ float As[BM][BK + 1];
  __shared__ float Bs[BN][BK + 1];
  const int tid = threadIdx.x;
  const int tx = tid % TX, ty = tid / TX;
  const int m0 = blockIdx.y * BM, n0 = blockIdx.x * BN;
  float acc[TM][TN] = {};
  constexpr int VPR = BK / 4;
  constexpr int RPP = 256 / VPR;
  const int lr = tid / VPR, lc = (tid % VPR) * 4;

  for (int k0 = 0; k0 < K; k0 += BK) {
    for (int r = lr; r < BM; r += RPP) {
      const size_t row = (size_t)(m0 + r);
      float4 v;
      if (AMODE == 0) {
        v = *(const float4*)&A[row * lda + k0 + lc];
      } else {
        float4 yv = *(const float4*)&A[row * 1024 + k0 + lc];
        float4 zv = *(const float4*)&A[row * 1024 + 512 + k0 + lc];
        v.x = yv.x * silu_f(zv.x); v.y = yv.y * silu_f(zv.y);
        v.z = yv.z * silu_f(zv.z); v.w = yv.w * silu_f(zv.w);
      }
      As[r][lc] = v.x; As[r][lc + 1] = v.y; As[r][lc + 2] = v.z; As[r][lc + 3] = v.w;
    }
    for (int r = lr; r < BN; r += RPP) {
      float4 v = *(const float4*)&Bw[(size_t)(n0 + r) * ldb + k0 + lc];
      Bs[r][lc] = v.x; Bs[r][lc + 1] = v.y; Bs[r][lc + 2] = v.z; Bs[r][lc + 3] = v.w;
    }
    __syncthreads();
    #pragma unroll
    for (int kk = 0; kk < BK; ++kk) {
      float a[TM], bb[TN];
      #pragma unroll
      for (int i = 0; i < TM; ++i) a[i] = As[ty * TM + i][kk];
      #pragma unroll
      for (int j = 0; j < TN; ++j) bb[j] = Bs[tx * TN + j][kk];
      #pragma unroll
      for (int i = 0; i < TM; ++i)
        #pragma unroll
        for (int j = 0; j < TN; ++j)
          acc[i][j] = fmaf(a[i], bb[j], acc[i][j]);
    }
    __syncthreads();
  }

  #pragma unroll
  for (int i = 0; i < TM; ++i) {
    const size_t gm = (size_t)m0 + ty * TM + i;
    #pragma unroll
    for (int j = 0; j < TN; ++j) {
      const int gn = n0 + tx * TN + j;
      float v = acc[i][j];
      if (EMODE == 2) C[gm * ldc + gn] += v;
      else            C[gm * ldc + gn] = v;
    }
  }
}

// ---------------------------------------------------------------------------
// bf16-MFMA GEMM, NT layout: C[m][n] = sum_k A[m][k] * W[n][k].
// fp32 inputs converted to bf16 (RNE) during LDS staging; fp32 accumulate.
// BM=128, BN=64, BK=32; 4 waves in 2x2, wave tile 64x32 (4x2 MFMA frags).
// mfma_f32_16x16x32_bf16: A-frag lane l = A[row=l&15][k=(l>>4)*8 +0..7]
// (one ds_read_b128); C/D: col=lane&15, row=(lane>>4)*4+reg  [m89/m91].
// LDS rows padded +8 bf16 (80B stride) -> ~2-way bank aliasing (free, m136).
// AMODE 0: plain A (lda). AMODE 1: y*silu(z) from XZ (stride 1024).
// EMODE 0: store. EMODE 2: C += v (residual).
// ---------------------------------------------------------------------------
template <int AMODE, int EMODE>
__global__ __launch_bounds__(256) void gemm_mfma(const float* __restrict__ A,
                                                 const float* __restrict__ W,
                                                 float* __restrict__ C,
                                                 int M, int N, int K,
                                                 int lda, int ldb, int ldc) {
  constexpr int BM = 128, BN = 64, BK = 32;
  __shared__ unsigned short As[BM][BK + 8];
  __shared__ unsigned short Bs[BN][BK + 8];
  const int tid = threadIdx.x;
  const int m0 = blockIdx.y * BM, n0 = blockIdx.x * BN;
  const int w = tid >> 6, lane = tid & 63;
  const int wm = (w >> 1) * 64, wn = (w & 1) * 32;   // wave tile origin
  const int fr = lane & 15, fk = (lane >> 4) * 8;    // fragment row / k-offset

  const int arow = tid >> 1, akh = (tid & 1) * 16;   // A staging: 16 elems/thread
  const int brow = tid >> 2, bq = (tid & 3) * 8;     // B staging: 8 elems/thread

  f32x4 acc[4][2] = {};

  for (int k0 = 0; k0 < K; k0 += BK) {
    // ---- stage A (fp32 -> bf16), optional gating ----
    {
      float v[16];
      if (AMODE == 0) {
        const float* s = &A[(size_t)(m0 + arow) * lda + k0 + akh];
        #pragma unroll
        for (int i = 0; i < 4; ++i) {
          float4 t = ((const float4*)s)[i];
          v[i * 4] = t.x; v[i * 4 + 1] = t.y; v[i * 4 + 2] = t.z; v[i * 4 + 3] = t.w;
        }
      } else {
        const float* sy = &A[(size_t)(m0 + arow) * 1024 + k0 + akh];
        #pragma unroll
        for (int i = 0; i < 4; ++i) {
          float4 ty = ((const float4*)sy)[i];
          float4 tz = ((const float4*)(sy + 512))[i];
          v[i * 4]     = ty.x * silu_f(tz.x); v[i * 4 + 1] = ty.y * silu_f(tz.y);
          v[i * 4 + 2] = ty.z * silu_f(tz.z); v[i * 4 + 3] = ty.w * silu_f(tz.w);
        }
      }
      u16x8 c0, c1;
      #pragma unroll
      for (int i = 0; i < 8; ++i) { c0[i] = f2bf(v[i]); c1[i] = f2bf(v[8 + i]); }
      *(u16x8*)&As[arow][akh] = c0;
      *(u16x8*)&As[arow][akh + 8] = c1;
    }
    // ---- stage B (weights fp32 -> bf16) ----
    {
      const float* s = &W[(size_t)(n0 + brow) * ldb + k0 + bq];
      float4 t0 = ((const float4*)s)[0], t1 = ((const float4*)s)[1];
      u16x8 c;
      c[0] = f2bf(t0.x); c[1] = f2bf(t0.y); c[2] = f2bf(t0.z); c[3] = f2bf(t0.w);
      c[4] = f2bf(t1.x); c[5] = f2bf(t1.y); c[6] = f2bf(t1.z); c[7] = f2bf(t1.w);
      *(u16x8*)&Bs[brow][bq] = c;
    }
    __syncthreads();
    // ---- fragments + MFMA ----
    bf16x8 af[4], bf[2];
    #pragma unroll
    for (int i = 0; i < 4; ++i) af[i] = *(const bf16x8*)&As[wm + i * 16 + fr][fk];
    #pragma unroll
    for (int j = 0; j < 2; ++j) bf[j] = *(const bf16x8*)&Bs[wn + j * 16 + fr][fk];
    #pragma unroll
    for (int i = 0; i < 4; ++i)
      #pragma unroll
      for (int j = 0; j < 2; ++j)
        acc[i][j] = __builtin_amdgcn_mfma_f32_16x16x32_bf16(af[i], bf[j], acc[i][j], 0, 0, 0);
    __syncthreads();
  }

  // ---- epilogue: col=lane&15, row=(lane>>4)*4+reg ----
  const int cr = (lane >> 4) * 4;
  #pragma unroll
  for (int i = 0; i < 4; ++i) {
    #pragma unroll
    for (int j = 0; j < 2; ++j) {
      #pragma unroll
      for (int r = 0; r < 4; ++r) {
        size_t idx = (size_t)(m0 + wm + i * 16 + cr + r) * ldc + (n0 + wn + j * 16 + fr);
        float v = acc[i][j][r];
        if (EMODE == 2) C[idx] += v;
        else            C[idx] = v;
      }
    }
  }
}

// ---------------------------------------------------------------------------
// Two-pass segmented selective scan, v3 (validated round 11).
// ---------------------------------------------------------------------------
__global__ __launch_bounds__(256) void scan3_kernel(const float* __restrict__ xc,
                                                    const float* __restrict__ dbc,
                                                    const float* __restrict__ dt_w,
                                                    const float* __restrict__ dt_b,
                                                    const float* __restrict__ A_log,
                                                    const float* __restrict__ Dskip,
                                                    float* __restrict__ y) {
  constexpr int NSEG = 64, TSEG = LSEQ / NSEG;
  __shared__ float lB[4][NSEG][16];
  __shared__ float lsum[4][NSEG];
  const int b = blockIdx.x;
  const int e0 = blockIdx.y * 4;
  const int tid = threadIdx.x;
  const int c = tid & 3, s = tid >> 2;
  const int e = e0 + c;

  float w[16], Ap[16];
  #pragma unroll
  for (int i = 0; i < 4; ++i) {
    float4 t4 = *(const float4*)&dt_w[e * 16 + i * 4];
    w[i * 4] = t4.x; w[i * 4 + 1] = t4.y; w[i * 4 + 2] = t4.z; w[i * 4 + 3] = t4.w;
  }
  #pragma unroll
  for (int n = 0; n < 16; ++n) Ap[n] = -expf(A_log[e * 16 + n]) * LOG2E;
  bool structured = true;
  #pragma unroll
  for (int n = 1; n < 16; ++n)
    structured = structured && (fabsf(Ap[n] - (n + 1) * Ap[0]) <= 1e-3f * (n + 1));
  const float bias = dt_b[e];
  const float dsk = Dskip[e];
  const size_t r0 = (size_t)b * LSEQ + (size_t)s * TSEG;

  auto calc_dA = [&](float dl, float* dA) {
    if (structured) {
      float a = exp2f(dl * Ap[0]);
      float p2 = a * a, p4, p8;
      p4 = p2 * p2; p8 = p4 * p4;
      dA[0] = a;          dA[1] = p2;         dA[2] = p2 * a;      dA[3] = p4;
      dA[4] = p4 * a;     dA[5] = p4 * p2;    dA[6] = p4 * dA[2];  dA[7] = p8;
      dA[8] = p8 * a;     dA[9] = p8 * p2;    dA[10] = p8 * dA[2]; dA[11] = p8 * p4;
      dA[12] = p8 * dA[4]; dA[13] = p8 * dA[5]; dA[14] = p8 * dA[6]; dA[15] = p8 * p8;
    } else {
      #pragma unroll
      for (int n = 0; n < 16; ++n) dA[n] = exp2f(dl * Ap[n]);
    }
  };

  float h[16];
  #pragma unroll
  for (int n = 0; n < 16; ++n) h[n] = 0.f;
  float sumd = 0.f;

  #pragma unroll 2
  for (int t = 0; t < TSEG; ++t) {
    const float* dr = &dbc[(r0 + t) * 48];
    float dl = bias;
    float Bv[16];
    #pragma unroll
    for (int i = 0; i < 4; ++i) {
      float4 dv = *(const float4*)&dr[i * 4];
      dl = fmaf(dv.x, w[i * 4], dl);     dl = fmaf(dv.y, w[i * 4 + 1], dl);
      dl = fmaf(dv.z, w[i * 4 + 2], dl); dl = fmaf(dv.w, w[i * 4 + 3], dl);
      float4 bv = *(const float4*)&dr[16 + i * 4];
      Bv[i * 4] = bv.x; Bv[i * 4 + 1] = bv.y; Bv[i * 4 + 2] = bv.z; Bv[i * 4 + 3] = bv.w;
    }
    dl = softplus_f(dl);
    sumd += dl;
    float x = xc[(r0 + t) * ED + e];
    float dx = dl * x;
    float dA[16];
    calc_dA(dl, dA);
    #pragma unroll
    for (int n = 0; n < 16; ++n)
      h[n] = fmaf(dA[n], h[n], dx * Bv[n]);
  }
  #pragma unroll
  for (int n = 0; n < 16; ++n) lB[c][s][n] = h[n];
  lsum[c][s] = sumd;
  __syncthreads();

  if (tid < 64) {
    const int cc = tid >> 4, nn = tid & 15;
    const float Apn = -expf(A_log[(e0 + cc) * 16 + nn]) * LOG2E;
    float H = 0.f;
    for (int ss = 0; ss < NSEG; ++ss) {
      float Bs = lB[cc][ss][nn];
      lB[cc][ss][nn] = H;
      H = fmaf(exp2f(Apn * lsum[cc][ss]), H, Bs);
    }
  }
  __syncthreads();

  #pragma unroll
  for (int n = 0; n < 16; ++n) h[n] = lB[c][s][n];
  #pragma unroll 2
  for (int t = 0; t < TSEG; ++t) {
    const float* dr = &dbc[(r0 + t) * 48];
    float dl = bias;
    float Bv[16], Cv[16];
    #pragma unroll
    for (int i = 0; i < 4; ++i) {
      float4 dv = *(const float4*)&dr[i * 4];
      dl = fmaf(dv.x, w[i * 4], dl);     dl = fmaf(dv.y, w[i * 4 + 1], dl);
      dl = fmaf(dv.z, w[i * 4 + 2], dl); dl = fmaf(dv.w, w[i * 4 + 3], dl);
      float4 bv = *(const float4*)&dr[16 + i * 4];
      Bv[i * 4] = bv.x; Bv[i * 4 + 1] = bv.y; Bv[i * 4 + 2] = bv.z; Bv[i * 4 + 3] = bv.w;
      float4 cv = *(const float4*)&dr[32 + i * 4];
      Cv[i * 4] = cv.x; Cv[i * 4 + 1] = cv.y; Cv[i * 4 + 2] = cv.z; Cv[i * 4 + 3] = cv.w;
    }
    dl = softplus_f(dl);
    float x = xc[(r0 + t) * ED + e];
    float dx = dl * x;
    float dA[16];
    calc_dA(dl, dA);
    float acc = 0.f;
    #pragma unroll
    for (int n = 0; n < 16; ++n) {
      h[n] = fmaf(dA[n], h[n], dx * Bv[n]);
      acc = fmaf(h[n], Cv[n], acc);
    }
    y[(r0 + t) * 1024 + e] = fmaf(dsk, x, acc);
  }
}

// ---------------------------------------------------------------------------
extern "C" void kernel_launch(void* const* d_in, const int* in_sizes, int n_in,
                              void* d_out, int out_size, void* d_ws, size_t ws_size,
                              hipStream_t stream) {
  const float* x      = (const float*)d_in[0];
  const float* in_w   = (const float*)d_in[1];
  const float* conv_w = (const float*)d_in[2];
  const float* conv_b = (const float*)d_in[3];
  const float* xp_w   = (const float*)d_in[4];
  const float* dt_w   = (const float*)d_in[5];
  const float* dt_b   = (const float*)d_in[6];
  const float* A_log  = (const float*)d_in[7];
  const float* Dsk    = (const float*)d_in[8];
  const float* out_w  = (const float*)d_in[9];
  const float* norm_w = (const float*)d_in[10];
  float* out = (float*)d_out;

  // Workspace layout (floats). Total = 30,146,560 floats = ~115 MiB.
  if (ws_size < 30146560ULL * 4ULL) return;
  float* ws  = (float*)d_ws;
  float* SEQ = ws;                  // 4,194,304   (B,L,D) residual stream
  float* XZ  = SEQ + 4194304;       // 16,777,216  (B,L,1024) [x_in | z]; y overwrites x_in
  float* XC  = XZ + 16777216;       // 8,388,608   (B,L,512) conv output
  float* DBC = XC + 8388608;        // 786,432     (B,L,48)
  float* TMP = XC;                  // alias: rmsnorm out, dead before conv writes XC

  // (B,D,L) -> (B,L,D)
  transpose_brc<<<dim3(LSEQ / 32, DM / 32, BSZ), dim3(32, 8), 0, stream>>>(x, SEQ, DM, LSEQ);

  for (int i = 0; i < 2; ++i) {
    rmsnorm_kernel<<<BSZ * LSEQ / 4, 256, 0, stream>>>(SEQ, norm_w + i * DM, TMP);
    // in_proj (bf16 MFMA): (16384,256) x (1024,256)^T -> XZ (ldc 1024)
    gemm_mfma<0, 0><<<dim3(1024 / 64, 16384 / 128), 256, 0, stream>>>(
        TMP, in_w + (size_t)i * 1024 * 256, XZ, 16384, 1024, 256, 256, 256, 1024);
    conv_silu_kernel<<<BSZ * LSEQ * 128 / 256, 256, 0, stream>>>(
        XZ, conv_w + i * ED * 4, conv_b + i * ED, XC);
    // x_proj (fp32): (16384,512) x (48,512)^T -> DBC
    gemm_nt<128, 48, 16, 8, 3, 0, 0><<<dim3(1, 16384 / 128), 256, 0, stream>>>(
        XC, xp_w + (size_t)i * 48 * 512, DBC, 16384, 48, 512, 512, 512, 48);
    // fused dt_proj + softplus + two-pass segmented selective scan (v3)
    scan3_kernel<<<dim3(BSZ, ED / 4), 256, 0, stream>>>(
        XC, DBC, dt_w + (size_t)i * ED * 16, dt_b + i * ED,
        A_log + (size_t)i * ED * NST, Dsk + i * ED, XZ);
    // out_proj (bf16 MFMA) on gated y*silu(z), accumulate into SEQ (residual)
    gemm_mfma<1, 2><<<dim3(256 / 64, 16384 / 128), 256, 0, stream>>>(
        XZ, out_w + (size_t)i * 256 * 512, SEQ, 16384, 256, 512, 1024, 512, 256);
  }

  // (B,L,D) -> (B,D,L)
  transpose_brc<<<dim3(DM / 32, LSEQ / 32, BSZ), dim3(32, 8), 0, stream>>>(SEQ, out, LSEQ, DM);
}